// Round 1
// baseline (3519.877 us; speedup 1.0000x reference)
//
#include <hip/hip_runtime.h>
#include <math.h>

// Problem constants
// B=4, C=64, OUT=64, H=256, W=256, M1=32, M2=32, HID=64, COORD=65

__device__ __forceinline__ float gelu_f(float v) {
    return 0.5f * v * (1.0f + erff(v * 0.70710678118654752440f));
}

// MLP 65 -> 64 (gelu) -> 64 (gelu) -> 64 (32 re + 32 im).
// Weight indices are wave-uniform -> compiler emits scalar loads.
__device__ __forceinline__ void mlp65(const float* __restrict__ in, // [65]
    const float* __restrict__ W0, const float* __restrict__ b0,
    const float* __restrict__ W1, const float* __restrict__ b1,
    const float* __restrict__ W2, const float* __restrict__ b2,
    float* __restrict__ ore, float* __restrict__ oim)           // [32] each
{
    float h0[64];
#pragma unroll
    for (int j = 0; j < 64; ++j) h0[j] = b0[j];
#pragma unroll
    for (int k = 0; k < 65; ++k) {
        float v = in[k];
#pragma unroll
        for (int j = 0; j < 64; ++j) h0[j] = fmaf(v, W0[k * 64 + j], h0[j]);
    }
#pragma unroll
    for (int j = 0; j < 64; ++j) h0[j] = gelu_f(h0[j]);

    float h1[64];
#pragma unroll
    for (int j = 0; j < 64; ++j) h1[j] = b1[j];
#pragma unroll
    for (int k = 0; k < 64; ++k) {
        float v = h0[k];
#pragma unroll
        for (int j = 0; j < 64; ++j) h1[j] = fmaf(v, W1[k * 64 + j], h1[j]);
    }
#pragma unroll
    for (int j = 0; j < 64; ++j) h1[j] = gelu_f(h1[j]);

    float o[64];
#pragma unroll
    for (int j = 0; j < 64; ++j) o[j] = b2[j];
#pragma unroll
    for (int k = 0; k < 64; ++k) {
        float v = h1[k];
#pragma unroll
        for (int j = 0; j < 64; ++j) o[j] = fmaf(v, W2[k * 64 + j], o[j]);
    }
#pragma unroll
    for (int j = 0; j < 32; ++j) { ore[j] = o[j]; oim[j] = o[32 + j]; }
}

// K1: wb basis. grid = B*H (1024), block = 256 (w). wb layout (B,H,W,M2)
__global__ __launch_bounds__(256) void k_wb(
    const float* __restrict__ x,
    const float* __restrict__ W0, const float* __restrict__ b0,
    const float* __restrict__ W1, const float* __restrict__ b1,
    const float* __restrict__ W2, const float* __restrict__ b2,
    float* __restrict__ wb_re, float* __restrict__ wb_im)
{
    int bh = blockIdx.x;
    int b = bh >> 8, h = bh & 255;
    int w = threadIdx.x;
    float in[65];
#pragma unroll
    for (int c = 0; c < 64; ++c)
        in[c] = x[((size_t)(b * 64 + c) * 256 + h) * 256 + w];
    in[64] = (float)w * (2.0f / 255.0f) - 1.0f;
    float ore[32], oim[32];
    mlp65(in, W0, b0, W1, b1, W2, b2, ore, oim);
    size_t p = ((size_t)bh * 256 + w) * 32;
#pragma unroll
    for (int m = 0; m < 32; ++m) { wb_re[p + m] = ore[m]; wb_im[p + m] = oim[m]; }
}

// K2: tfw[b,c,h,m] = sum_w x[b,c,h,w] * wb[b,h,w,m]  (x real)
// grid = B*H (1024), block = 256. LDS = 64KB exactly (wb row [w][m]).
// Also writes tfwT (B,M2,H,C) real part for the h-MLP gather.
__global__ __launch_bounds__(256) void k_tfw(
    const float* __restrict__ x,
    const float* __restrict__ wb_re, const float* __restrict__ wb_im,
    float* __restrict__ tfw_re, float* __restrict__ tfw_im,
    float* __restrict__ tfwT_re)
{
    __shared__ float wr[256 * 32];
    __shared__ float wi[256 * 32];
    int bh = blockIdx.x;
    int b = bh >> 8, h = bh & 255;
    int t = threadIdx.x;
    size_t wboff = (size_t)bh * 8192;
#pragma unroll
    for (int i = 0; i < 8; ++i) {
        int idx = i * 256 + t;
        *(float4*)&wr[idx * 4] = *(const float4*)&wb_re[wboff + (size_t)idx * 4];
        *(float4*)&wi[idx * 4] = *(const float4*)&wb_im[wboff + (size_t)idx * 4];
    }
    __syncthreads();
    int m = t & 31, cg = t >> 5;   // each thread: 8 c's = cg*8+i
    float ar[8], ai[8];
#pragma unroll
    for (int i = 0; i < 8; ++i) { ar[i] = 0.f; ai[i] = 0.f; }
    for (int w4 = 0; w4 < 256; w4 += 4) {
        float4 xv[8];
#pragma unroll
        for (int i = 0; i < 8; ++i)
            xv[i] = *(const float4*)&x[((size_t)(b * 64 + cg * 8 + i) * 256 + h) * 256 + w4];
#pragma unroll
        for (int q = 0; q < 4; ++q) {
            float wrv = wr[(w4 + q) * 32 + m];
            float wiv = wi[(w4 + q) * 32 + m];
#pragma unroll
            for (int i = 0; i < 8; ++i) {
                float xq = (q == 0) ? xv[i].x : (q == 1) ? xv[i].y : (q == 2) ? xv[i].z : xv[i].w;
                ar[i] = fmaf(xq, wrv, ar[i]);
                ai[i] = fmaf(xq, wiv, ai[i]);
            }
        }
    }
#pragma unroll
    for (int i = 0; i < 8; ++i) {
        int c = cg * 8 + i;
        size_t po = ((size_t)(b * 64 + c) * 256 + h) * 32 + m;
        tfw_re[po] = ar[i];
        tfw_im[po] = ai[i];
        tfwT_re[((size_t)(b * 32 + m) * 256 + h) * 64 + c] = ar[i];
    }
}

// K3: hb basis. grid = B*M2 (128), block = 256 (h). hb layout (B,M2,H,M1)
__global__ __launch_bounds__(256) void k_hb(
    const float* __restrict__ tfwT_re,
    const float* __restrict__ W0, const float* __restrict__ b0,
    const float* __restrict__ W1, const float* __restrict__ b1,
    const float* __restrict__ W2, const float* __restrict__ b2,
    float* __restrict__ hb_re, float* __restrict__ hb_im)
{
    int bm = blockIdx.x;   // b*32+m
    int h = threadIdx.x;
    float in[65];
    const float* src = tfwT_re + ((size_t)bm * 256 + h) * 64;
#pragma unroll
    for (int c = 0; c < 64; c += 4) {
        float4 v = *(const float4*)&src[c];
        in[c] = v.x; in[c + 1] = v.y; in[c + 2] = v.z; in[c + 3] = v.w;
    }
    in[64] = (float)h * (2.0f / 255.0f) - 1.0f;
    float ore[32], oim[32];
    mlp65(in, W0, b0, W1, b1, W2, b2, ore, oim);
    size_t p = ((size_t)bm * 256 + h) * 32;
#pragma unroll
    for (int k = 0; k < 32; ++k) { hb_re[p + k] = ore[k]; hb_im[p + k] = oim[k]; }
}

// K4: tfhw[b,c,k,m] = sum_h tfw[b,c,h,m] * hb[b,m,h,k]   (complex*complex)
// grid = B*M2*2 (256): (b,m,chalf). block = 256: lanes (k, cg), 4 c each.
__global__ __launch_bounds__(256) void k_tfhw(
    const float* __restrict__ tfw_re, const float* __restrict__ tfw_im,
    const float* __restrict__ hb_re, const float* __restrict__ hb_im,
    float* __restrict__ tfhw_re, float* __restrict__ tfhw_im)
{
    __shared__ float hr[256 * 32];
    __shared__ float hi2[256 * 32];
    int blk = blockIdx.x;
    int bm = blk >> 1, chalf = blk & 1;
    int b = bm >> 5, m = bm & 31;
    int t = threadIdx.x;
    size_t hboff = (size_t)bm * 8192;
#pragma unroll
    for (int i = 0; i < 8; ++i) {
        int idx = i * 256 + t;
        *(float4*)&hr[idx * 4] = *(const float4*)&hb_re[hboff + (size_t)idx * 4];
        *(float4*)&hi2[idx * 4] = *(const float4*)&hb_im[hboff + (size_t)idx * 4];
    }
    __syncthreads();
    int k = t & 31, cg = t >> 5;   // c = chalf*32 + cg*4 + i
    float accr[4] = {0.f, 0.f, 0.f, 0.f}, acci[4] = {0.f, 0.f, 0.f, 0.f};
    for (int h = 0; h < 256; ++h) {
        float hrv = hr[h * 32 + k];
        float hiv = hi2[h * 32 + k];
#pragma unroll
        for (int i = 0; i < 4; ++i) {
            int c = chalf * 32 + cg * 4 + i;
            size_t ta = ((size_t)(b * 64 + c) * 256 + h) * 32 + m;
            float tr = tfw_re[ta], ti = tfw_im[ta];
            accr[i] = fmaf(tr, hrv, fmaf(-ti, hiv, accr[i]));
            acci[i] = fmaf(tr, hiv, fmaf(ti, hrv, acci[i]));
        }
    }
#pragma unroll
    for (int i = 0; i < 4; ++i) {
        int c = chalf * 32 + cg * 4 + i;
        size_t po = ((size_t)(b * 64 + c) * 32 + k) * 32 + m;
        tfhw_re[po] = accr[i];
        tfhw_im[po] = acci[i];
    }
}

// K5: proc[b,o,k,m] = sum_c tfhw[b,c,k,m] * Wf[c,o,k,m]
// grid = 256: (o, kq). block = 256 (one mode each, 4 batches).
__global__ __launch_bounds__(256) void k_proc(
    const float* __restrict__ tfhw_re, const float* __restrict__ tfhw_im,
    const float* __restrict__ Wf_re, const float* __restrict__ Wf_im,
    float* __restrict__ proc_re, float* __restrict__ proc_im)
{
    int o = blockIdx.x >> 2, kq = blockIdx.x & 3;
    int t = threadIdx.x;
    int mo = kq * 256 + t;   // mode index k*32+m within 1024
    float accr[4] = {0.f, 0.f, 0.f, 0.f}, acci[4] = {0.f, 0.f, 0.f, 0.f};
    for (int c = 0; c < 64; ++c) {
        float wfr = Wf_re[(size_t)(c * 64 + o) * 1024 + mo];
        float wfi = Wf_im[(size_t)(c * 64 + o) * 1024 + mo];
#pragma unroll
        for (int bb = 0; bb < 4; ++bb) {
            float tr = tfhw_re[(size_t)(bb * 64 + c) * 1024 + mo];
            float ti = tfhw_im[(size_t)(bb * 64 + c) * 1024 + mo];
            accr[bb] = fmaf(tr, wfr, fmaf(-ti, wfi, accr[bb]));
            acci[bb] = fmaf(tr, wfi, fmaf(ti, wfr, acci[bb]));
        }
    }
#pragma unroll
    for (int bb = 0; bb < 4; ++bb) {
        proc_re[(size_t)(bb * 64 + o) * 1024 + mo] = accr[bb];
        proc_im[(size_t)(bb * 64 + o) * 1024 + mo] = acci[bb];
    }
}

// K6: rec[b,o,h,m] = sum_k proc[b,o,k,m] * conj(hb[b,m,h,k])
// grid = 512: (b,m,hq). block = 256: lanes o(64) x hg(4), 16 h each.
// rec layout (B,OUT,H,M2) so K7 can scalar-load contiguously.
__global__ __launch_bounds__(256) void k_rec(
    const float* __restrict__ proc_re, const float* __restrict__ proc_im,
    const float* __restrict__ hb_re, const float* __restrict__ hb_im,
    float* __restrict__ rec_re, float* __restrict__ rec_im)
{
    int blk = blockIdx.x;
    int bm = blk >> 2, hq = blk & 3;
    int b = bm >> 5, m = bm & 31;
    int t = threadIdx.x;
    int o = t & 63, hg = t >> 6;
    float Pr[32], Pi[32];
#pragma unroll
    for (int k = 0; k < 32; ++k) {
        size_t pa = ((size_t)(b * 64 + o) * 32 + k) * 32 + m;
        Pr[k] = proc_re[pa];
        Pi[k] = proc_im[pa];
    }
    int h0 = hq * 64 + hg * 16;
    for (int hh = 0; hh < 16; ++hh) {
        int h = h0 + hh;
        const float* hbr = hb_re + ((size_t)bm * 256 + h) * 32;
        const float* hbi = hb_im + ((size_t)bm * 256 + h) * 32;
        float ar = 0.f, ai = 0.f;
#pragma unroll
        for (int k = 0; k < 32; ++k) {
            float hrv = hbr[k], hiv = hbi[k];
            // proc * conj(hb): re = pr*hr + pi*hi ; im = pi*hr - pr*hi
            ar = fmaf(Pr[k], hrv, fmaf(Pi[k], hiv, ar));
            ai = fmaf(Pi[k], hrv, fmaf(-Pr[k], hiv, ai));
        }
        size_t ra = ((size_t)(b * 64 + o) * 256 + h) * 32 + m;
        rec_re[ra] = ar;
        rec_im[ra] = ai;
    }
}

// K7: spatial + mixer + skip + gelus, fused. grid = B*H (1024), block=256 (w).
__global__ __launch_bounds__(256) void k_final(
    const float* __restrict__ x,
    const float* __restrict__ wb_re, const float* __restrict__ wb_im,
    const float* __restrict__ rec_re, const float* __restrict__ rec_im,
    const float* __restrict__ mw, const float* __restrict__ mb,
    const float* __restrict__ scw, const float* __restrict__ scb,
    float* __restrict__ out)
{
    int bh = blockIdx.x;
    int b = bh >> 8, h = bh & 255;
    int w = threadIdx.x;
    float wrv[32], wiv[32];
    const float* wbp = wb_re + ((size_t)bh * 256 + w) * 32;
    const float* wip = wb_im + ((size_t)bh * 256 + w) * 32;
#pragma unroll
    for (int m = 0; m < 32; m += 4) {
        float4 v = *(const float4*)&wbp[m];
        wrv[m] = v.x; wrv[m + 1] = v.y; wrv[m + 2] = v.z; wrv[m + 3] = v.w;
        float4 u = *(const float4*)&wip[m];
        wiv[m] = u.x; wiv[m + 1] = u.y; wiv[m + 2] = u.z; wiv[m + 3] = u.w;
    }
    float sp[64];
#pragma unroll
    for (int o = 0; o < 64; ++o) {
        const float* rr = rec_re + ((size_t)(b * 64 + o) * 256 + h) * 32;
        const float* ri = rec_im + ((size_t)(b * 64 + o) * 256 + h) * 32;
        float acc = 0.f;
#pragma unroll
        for (int m = 0; m < 32; ++m)
            acc = fmaf(rr[m], wrv[m], fmaf(ri[m], wiv[m], acc));
        sp[o] = acc * (1.0f / 65536.0f);
    }
    float xv[64];
#pragma unroll
    for (int c = 0; c < 64; ++c)
        xv[c] = x[((size_t)(b * 64 + c) * 256 + h) * 256 + w];
    for (int o = 0; o < 64; ++o) {
        float a = mb[o];
#pragma unroll
        for (int c = 0; c < 64; ++c) a = fmaf(mw[o * 64 + c], sp[c], a);
        a = gelu_f(a);
        float a2 = a + scb[o];
#pragma unroll
        for (int c = 0; c < 64; ++c) a2 = fmaf(scw[o * 64 + c], xv[c], a2);
        out[((size_t)(b * 64 + o) * 256 + h) * 256 + w] = gelu_f(a2);
    }
}

extern "C" void kernel_launch(void* const* d_in, const int* in_sizes, int n_in,
                              void* d_out, int out_size, void* d_ws, size_t ws_size,
                              hipStream_t stream) {
    const float* x    = (const float*)d_in[0];
    const float* wW0  = (const float*)d_in[1];
    const float* wb0  = (const float*)d_in[2];
    const float* wW1  = (const float*)d_in[3];
    const float* wb1  = (const float*)d_in[4];
    const float* wW2  = (const float*)d_in[5];
    const float* wb2  = (const float*)d_in[6];
    const float* hW0  = (const float*)d_in[7];
    const float* hb0  = (const float*)d_in[8];
    const float* hW1  = (const float*)d_in[9];
    const float* hb1  = (const float*)d_in[10];
    const float* hW2  = (const float*)d_in[11];
    const float* hb2  = (const float*)d_in[12];
    const float* Wf_re = (const float*)d_in[13];
    const float* Wf_im = (const float*)d_in[14];
    const float* mw   = (const float*)d_in[15];
    const float* mbv  = (const float*)d_in[16];
    const float* scw  = (const float*)d_in[17];
    const float* scb  = (const float*)d_in[18];

    float* ws = (float*)d_ws;
    float* wb_re   = ws;                       // 8388608
    float* wb_im   = wb_re + 8388608;          // 8388608
    float* tfw_re  = wb_im + 8388608;          // 2097152
    float* tfw_im  = tfw_re + 2097152;         // 2097152
    float* tfwT    = tfw_im + 2097152;         // 2097152
    float* hb_re   = tfwT + 2097152;           // 1048576
    float* hb_im   = hb_re + 1048576;          // 1048576
    float* tfhw_re = hb_im + 1048576;          // 262144
    float* tfhw_im = tfhw_re + 262144;         // 262144
    float* proc_re = tfhw_im + 262144;         // 262144
    float* proc_im = proc_re + 262144;         // 262144
    float* rec_re  = proc_im + 262144;         // 2097152
    float* rec_im  = rec_re + 2097152;         // 2097152
    // total 30,408,704 floats = 121.6 MB

    k_wb<<<1024, 256, 0, stream>>>(x, wW0, wb0, wW1, wb1, wW2, wb2, wb_re, wb_im);
    k_tfw<<<1024, 256, 0, stream>>>(x, wb_re, wb_im, tfw_re, tfw_im, tfwT);
    k_hb<<<128, 256, 0, stream>>>(tfwT, hW0, hb0, hW1, hb1, hW2, hb2, hb_re, hb_im);
    k_tfhw<<<256, 256, 0, stream>>>(tfw_re, tfw_im, hb_re, hb_im, tfhw_re, tfhw_im);
    k_proc<<<256, 256, 0, stream>>>(tfhw_re, tfhw_im, Wf_re, Wf_im, proc_re, proc_im);
    k_rec<<<512, 256, 0, stream>>>(proc_re, proc_im, hb_re, hb_im, rec_re, rec_im);
    k_final<<<1024, 256, 0, stream>>>(x, wb_re, wb_im, rec_re, rec_im, mw, mbv, scw, scb,
                                      (float*)d_out);
}

// Round 2
// 921.650 us; speedup vs baseline: 3.8191x; 3.8191x over previous
//
#include <hip/hip_runtime.h>
#include <math.h>

// Problem constants: B=4, C=64, OUT=64, H=256, W=256, M1=32, M2=32, HID=64, COORD=65

__device__ __forceinline__ float gelu_f(float v) {
    return 0.5f * v * (1.0f + erff(v * 0.70710678118654752440f));
}

// ---------------------------------------------------------------------------
// MLP layer tile: 256 threads compute [64 pixels] x [64 outs].
// act: LDS [64][68] (row stride 68 floats, 16B-aligned rows).
// W: global row-major [K][64]; bias: [64].
// Thread (po = t>>4, oo = t&15) computes acc[4 pixels][4 outs].
// K4 = number of k-quads (16 for K=64); extra = add k=64 (coord) term.
// ---------------------------------------------------------------------------
__device__ __forceinline__ void mlp_layer(
    const float* __restrict__ act,
    const float* __restrict__ W,
    const float* __restrict__ bias,
    bool extra, int t, float acc[4][4])
{
    const int po = t >> 4, oo = t & 15;
    const float4 bv = *(const float4*)&bias[oo * 4];
#pragma unroll
    for (int i = 0; i < 4; ++i) {
        acc[i][0] = bv.x; acc[i][1] = bv.y; acc[i][2] = bv.z; acc[i][3] = bv.w;
    }
#pragma unroll
    for (int k4 = 0; k4 < 16; ++k4) {
        float4 a[4], w[4];
#pragma unroll
        for (int i = 0; i < 4; ++i)
            a[i] = *(const float4*)&act[(po * 4 + i) * 68 + k4 * 4];
#pragma unroll
        for (int q = 0; q < 4; ++q)
            w[q] = *(const float4*)&W[(k4 * 4 + q) * 64 + oo * 4];
#pragma unroll
        for (int i = 0; i < 4; ++i) {
            const float aq[4] = {a[i].x, a[i].y, a[i].z, a[i].w};
#pragma unroll
            for (int q = 0; q < 4; ++q) {
                acc[i][0] = fmaf(aq[q], w[q].x, acc[i][0]);
                acc[i][1] = fmaf(aq[q], w[q].y, acc[i][1]);
                acc[i][2] = fmaf(aq[q], w[q].z, acc[i][2]);
                acc[i][3] = fmaf(aq[q], w[q].w, acc[i][3]);
            }
        }
    }
    if (extra) {
        const float4 wv = *(const float4*)&W[64 * 64 + oo * 4];
#pragma unroll
        for (int i = 0; i < 4; ++i) {
            const float av = act[(po * 4 + i) * 68 + 64];
            acc[i][0] = fmaf(av, wv.x, acc[i][0]);
            acc[i][1] = fmaf(av, wv.y, acc[i][1]);
            acc[i][2] = fmaf(av, wv.z, acc[i][2]);
            acc[i][3] = fmaf(av, wv.w, acc[i][3]);
        }
    }
}

__device__ __forceinline__ float4 gelu4(const float a[4]) {
    float4 r;
    r.x = gelu_f(a[0]); r.y = gelu_f(a[1]); r.z = gelu_f(a[2]); r.w = gelu_f(a[3]);
    return r;
}

// K1: wb basis via tiled MLP. grid = B*H*4 (4096): (b,h,wq). 64 pixels/block.
__global__ __launch_bounds__(256) void k_wb_mlp(
    const float* __restrict__ x,
    const float* __restrict__ W0, const float* __restrict__ b0,
    const float* __restrict__ W1, const float* __restrict__ b1,
    const float* __restrict__ W2, const float* __restrict__ b2,
    float* __restrict__ wb_re, float* __restrict__ wb_im)
{
    __shared__ __align__(16) float a0[64 * 68];
    __shared__ __align__(16) float a1[64 * 68];
    const int blk = blockIdx.x;
    const int b = blk >> 10, h = (blk >> 2) & 255, wq = blk & 3;
    const int w0 = wq * 64;
    const int t = threadIdx.x;
    // stage x transposed: a0[w_local][c]
#pragma unroll
    for (int r = 0; r < 4; ++r) {
        const int idx = r * 256 + t;
        const int c = idx >> 4, wg = idx & 15;
        const float4 v = *(const float4*)&x[((size_t)(b * 64 + c) * 256 + h) * 256 + w0 + wg * 4];
        a0[(wg * 4 + 0) * 68 + c] = v.x;
        a0[(wg * 4 + 1) * 68 + c] = v.y;
        a0[(wg * 4 + 2) * 68 + c] = v.z;
        a0[(wg * 4 + 3) * 68 + c] = v.w;
    }
    if (t < 64) a0[t * 68 + 64] = (float)(w0 + t) * (2.0f / 255.0f) - 1.0f;
    __syncthreads();

    const int po = t >> 4, oo = t & 15;
    float acc[4][4];
    mlp_layer(a0, W0, b0, true, t, acc);
    __syncthreads();  // a1 unused yet, but keep write/read ordering simple
#pragma unroll
    for (int i = 0; i < 4; ++i)
        *(float4*)&a1[(po * 4 + i) * 68 + oo * 4] = gelu4(acc[i]);
    __syncthreads();
    mlp_layer(a1, W1, b1, false, t, acc);
    __syncthreads();
#pragma unroll
    for (int i = 0; i < 4; ++i)
        *(float4*)&a0[(po * 4 + i) * 68 + oo * 4] = gelu4(acc[i]);
    __syncthreads();
    mlp_layer(a0, W2, b2, false, t, acc);

    const size_t pixbase = (size_t)(b * 256 + h) * 256 + w0;
#pragma unroll
    for (int i = 0; i < 4; ++i) {
        const size_t pix = pixbase + po * 4 + i;
        float4 v; v.x = acc[i][0]; v.y = acc[i][1]; v.z = acc[i][2]; v.w = acc[i][3];
        if (oo < 8) *(float4*)&wb_re[pix * 32 + oo * 4] = v;
        else        *(float4*)&wb_im[pix * 32 + (oo - 8) * 4] = v;
    }
}

// K3: hb basis via tiled MLP. grid = B*M2*4 (512): (bm,hq). input tfwT [pixel][64].
__global__ __launch_bounds__(256) void k_hb_mlp(
    const float* __restrict__ tfwT,
    const float* __restrict__ W0, const float* __restrict__ b0,
    const float* __restrict__ W1, const float* __restrict__ b1,
    const float* __restrict__ W2, const float* __restrict__ b2,
    float* __restrict__ hb_re, float* __restrict__ hb_im)
{
    __shared__ __align__(16) float a0[64 * 68];
    __shared__ __align__(16) float a1[64 * 68];
    const int blk = blockIdx.x;
    const int bm = blk >> 2, hq = blk & 3;
    const int h0 = hq * 64;
    const int t = threadIdx.x;
#pragma unroll
    for (int r = 0; r < 4; ++r) {
        const int idx = r * 256 + t;
        const int p = idx >> 4, f = idx & 15;
        const float4 v = *(const float4*)&tfwT[((size_t)bm * 256 + h0 + p) * 64 + f * 4];
        *(float4*)&a0[p * 68 + f * 4] = v;
    }
    if (t < 64) a0[t * 68 + 64] = (float)(h0 + t) * (2.0f / 255.0f) - 1.0f;
    __syncthreads();

    const int po = t >> 4, oo = t & 15;
    float acc[4][4];
    mlp_layer(a0, W0, b0, true, t, acc);
    __syncthreads();
#pragma unroll
    for (int i = 0; i < 4; ++i)
        *(float4*)&a1[(po * 4 + i) * 68 + oo * 4] = gelu4(acc[i]);
    __syncthreads();
    mlp_layer(a1, W1, b1, false, t, acc);
    __syncthreads();
#pragma unroll
    for (int i = 0; i < 4; ++i)
        *(float4*)&a0[(po * 4 + i) * 68 + oo * 4] = gelu4(acc[i]);
    __syncthreads();
    mlp_layer(a0, W2, b2, false, t, acc);

    const size_t pixbase = (size_t)bm * 256 + h0;
#pragma unroll
    for (int i = 0; i < 4; ++i) {
        const size_t pix = pixbase + po * 4 + i;
        float4 v; v.x = acc[i][0]; v.y = acc[i][1]; v.z = acc[i][2]; v.w = acc[i][3];
        if (oo < 8) *(float4*)&hb_re[pix * 32 + oo * 4] = v;
        else        *(float4*)&hb_im[pix * 32 + (oo - 8) * 4] = v;
    }
}

// K2: tfw[b,c,h,m] = sum_w x[b,c,h,w] * wb[b,h,w,m]  (x real)
__global__ __launch_bounds__(256) void k_tfw(
    const float* __restrict__ x,
    const float* __restrict__ wb_re, const float* __restrict__ wb_im,
    float* __restrict__ tfw_re, float* __restrict__ tfw_im,
    float* __restrict__ tfwT_re)
{
    __shared__ float wr[256 * 32];
    __shared__ float wi[256 * 32];
    int bh = blockIdx.x;
    int b = bh >> 8, h = bh & 255;
    int t = threadIdx.x;
    size_t wboff = (size_t)bh * 8192;
#pragma unroll
    for (int i = 0; i < 8; ++i) {
        int idx = i * 256 + t;
        *(float4*)&wr[idx * 4] = *(const float4*)&wb_re[wboff + (size_t)idx * 4];
        *(float4*)&wi[idx * 4] = *(const float4*)&wb_im[wboff + (size_t)idx * 4];
    }
    __syncthreads();
    int m = t & 31, cg = t >> 5;
    float ar[8], ai[8];
#pragma unroll
    for (int i = 0; i < 8; ++i) { ar[i] = 0.f; ai[i] = 0.f; }
    for (int w4 = 0; w4 < 256; w4 += 4) {
        float4 xv[8];
#pragma unroll
        for (int i = 0; i < 8; ++i)
            xv[i] = *(const float4*)&x[((size_t)(b * 64 + cg * 8 + i) * 256 + h) * 256 + w4];
#pragma unroll
        for (int q = 0; q < 4; ++q) {
            float wrv = wr[(w4 + q) * 32 + m];
            float wiv = wi[(w4 + q) * 32 + m];
#pragma unroll
            for (int i = 0; i < 8; ++i) {
                float xq = (q == 0) ? xv[i].x : (q == 1) ? xv[i].y : (q == 2) ? xv[i].z : xv[i].w;
                ar[i] = fmaf(xq, wrv, ar[i]);
                ai[i] = fmaf(xq, wiv, ai[i]);
            }
        }
    }
#pragma unroll
    for (int i = 0; i < 8; ++i) {
        int c = cg * 8 + i;
        size_t po = ((size_t)(b * 64 + c) * 256 + h) * 32 + m;
        tfw_re[po] = ar[i];
        tfw_im[po] = ai[i];
        tfwT_re[((size_t)(b * 32 + m) * 256 + h) * 64 + c] = ar[i];
    }
}

// K4: tfhw[b,c,k,m] = sum_h tfw[b,c,h,m] * hb[b,m,h,k]
__global__ __launch_bounds__(256) void k_tfhw(
    const float* __restrict__ tfw_re, const float* __restrict__ tfw_im,
    const float* __restrict__ hb_re, const float* __restrict__ hb_im,
    float* __restrict__ tfhw_re, float* __restrict__ tfhw_im)
{
    __shared__ float hr[256 * 32];
    __shared__ float hi2[256 * 32];
    int blk = blockIdx.x;
    int bm = blk >> 1, chalf = blk & 1;
    int b = bm >> 5, m = bm & 31;
    int t = threadIdx.x;
    size_t hboff = (size_t)bm * 8192;
#pragma unroll
    for (int i = 0; i < 8; ++i) {
        int idx = i * 256 + t;
        *(float4*)&hr[idx * 4] = *(const float4*)&hb_re[hboff + (size_t)idx * 4];
        *(float4*)&hi2[idx * 4] = *(const float4*)&hb_im[hboff + (size_t)idx * 4];
    }
    __syncthreads();
    int k = t & 31, cg = t >> 5;
    float accr[4] = {0.f, 0.f, 0.f, 0.f}, acci[4] = {0.f, 0.f, 0.f, 0.f};
    for (int h = 0; h < 256; ++h) {
        float hrv = hr[h * 32 + k];
        float hiv = hi2[h * 32 + k];
#pragma unroll
        for (int i = 0; i < 4; ++i) {
            int c = chalf * 32 + cg * 4 + i;
            size_t ta = ((size_t)(b * 64 + c) * 256 + h) * 32 + m;
            float tr = tfw_re[ta], ti = tfw_im[ta];
            accr[i] = fmaf(tr, hrv, fmaf(-ti, hiv, accr[i]));
            acci[i] = fmaf(tr, hiv, fmaf(ti, hrv, acci[i]));
        }
    }
#pragma unroll
    for (int i = 0; i < 4; ++i) {
        int c = chalf * 32 + cg * 4 + i;
        size_t po = ((size_t)(b * 64 + c) * 32 + k) * 32 + m;
        tfhw_re[po] = accr[i];
        tfhw_im[po] = acci[i];
    }
}

// K5: proc[b,o,k,m] = sum_c tfhw[b,c,k,m] * Wf[c,o,k,m]
__global__ __launch_bounds__(256) void k_proc(
    const float* __restrict__ tfhw_re, const float* __restrict__ tfhw_im,
    const float* __restrict__ Wf_re, const float* __restrict__ Wf_im,
    float* __restrict__ proc_re, float* __restrict__ proc_im)
{
    int o = blockIdx.x >> 2, kq = blockIdx.x & 3;
    int t = threadIdx.x;
    int mo = kq * 256 + t;
    float accr[4] = {0.f, 0.f, 0.f, 0.f}, acci[4] = {0.f, 0.f, 0.f, 0.f};
    for (int c = 0; c < 64; ++c) {
        float wfr = Wf_re[(size_t)(c * 64 + o) * 1024 + mo];
        float wfi = Wf_im[(size_t)(c * 64 + o) * 1024 + mo];
#pragma unroll
        for (int bb = 0; bb < 4; ++bb) {
            float tr = tfhw_re[(size_t)(bb * 64 + c) * 1024 + mo];
            float ti = tfhw_im[(size_t)(bb * 64 + c) * 1024 + mo];
            accr[bb] = fmaf(tr, wfr, fmaf(-ti, wfi, accr[bb]));
            acci[bb] = fmaf(tr, wfi, fmaf(ti, wfr, acci[bb]));
        }
    }
#pragma unroll
    for (int bb = 0; bb < 4; ++bb) {
        proc_re[(size_t)(bb * 64 + o) * 1024 + mo] = accr[bb];
        proc_im[(size_t)(bb * 64 + o) * 1024 + mo] = acci[bb];
    }
}

// K6: rec[b,o,h,m] = sum_k proc[b,o,k,m] * conj(hb[b,m,h,k])
__global__ __launch_bounds__(256) void k_rec(
    const float* __restrict__ proc_re, const float* __restrict__ proc_im,
    const float* __restrict__ hb_re, const float* __restrict__ hb_im,
    float* __restrict__ rec_re, float* __restrict__ rec_im)
{
    int blk = blockIdx.x;
    int bm = blk >> 2, hq = blk & 3;
    int b = bm >> 5, m = bm & 31;
    int t = threadIdx.x;
    int o = t & 63, hg = t >> 6;
    float Pr[32], Pi[32];
#pragma unroll
    for (int k = 0; k < 32; ++k) {
        size_t pa = ((size_t)(b * 64 + o) * 32 + k) * 32 + m;
        Pr[k] = proc_re[pa];
        Pi[k] = proc_im[pa];
    }
    int h0 = hq * 64 + hg * 16;
    for (int hh = 0; hh < 16; ++hh) {
        int h = h0 + hh;
        const float* hbr = hb_re + ((size_t)bm * 256 + h) * 32;
        const float* hbi = hb_im + ((size_t)bm * 256 + h) * 32;
        float ar = 0.f, ai = 0.f;
#pragma unroll
        for (int k = 0; k < 32; ++k) {
            float hrv = hbr[k], hiv = hbi[k];
            ar = fmaf(Pr[k], hrv, fmaf(Pi[k], hiv, ar));
            ai = fmaf(Pi[k], hrv, fmaf(-Pr[k], hiv, ai));
        }
        size_t ra = ((size_t)(b * 64 + o) * 256 + h) * 32 + m;
        rec_re[ra] = ar;
        rec_im[ra] = ai;
    }
}

// K7: spatial + mixer + skip + gelus. grid = B*H*2 (2048): (b,h,wq). 128 px/block,
// each pixel split across 2 threads (32 outputs each). LDS stages x and sp.
__global__ __launch_bounds__(256) void k_final2(
    const float* __restrict__ x,
    const float* __restrict__ wb_re, const float* __restrict__ wb_im,
    const float* __restrict__ rec_re, const float* __restrict__ rec_im,
    const float* __restrict__ mw, const float* __restrict__ mb,
    const float* __restrict__ scw, const float* __restrict__ scb,
    float* __restrict__ out)
{
    __shared__ __align__(16) float xl[64 * 132];
    __shared__ __align__(16) float sl[64 * 132];
    const int blk = blockIdx.x;
    const int b = blk >> 9, h = (blk >> 1) & 255, wq = blk & 1;
    const int w0 = wq * 128;
    const int t = threadIdx.x;
    const int p = t & 127, half = t >> 7;

    // stage x: xl[c][p]
#pragma unroll
    for (int r = 0; r < 8; ++r) {
        const int idx = r * 256 + t;
        const int c = idx >> 5, wg = idx & 31;
        const float4 v = *(const float4*)&x[((size_t)(b * 64 + c) * 256 + h) * 256 + w0 + wg * 4];
        *(float4*)&xl[c * 132 + wg * 4] = v;
    }

    // wb for this pixel
    float wr[32], wi[32];
    {
        const float* wbp = &wb_re[((size_t)(b * 256 + h) * 256 + w0 + p) * 32];
        const float* wip = &wb_im[((size_t)(b * 256 + h) * 256 + w0 + p) * 32];
#pragma unroll
        for (int m4 = 0; m4 < 8; ++m4) {
            const float4 v = *(const float4*)&wbp[m4 * 4];
            wr[m4 * 4] = v.x; wr[m4 * 4 + 1] = v.y; wr[m4 * 4 + 2] = v.z; wr[m4 * 4 + 3] = v.w;
            const float4 u = *(const float4*)&wip[m4 * 4];
            wi[m4 * 4] = u.x; wi[m4 * 4 + 1] = u.y; wi[m4 * 4 + 2] = u.z; wi[m4 * 4 + 3] = u.w;
        }
    }

    // phase 1: sp for my 32 outputs -> sl[o][p]
#pragma unroll
    for (int oj = 0; oj < 32; ++oj) {
        const int o = half * 32 + oj;
        const float* rr = &rec_re[((size_t)(b * 64 + o) * 256 + h) * 32];
        const float* ri = &rec_im[((size_t)(b * 64 + o) * 256 + h) * 32];
        float acc = 0.f;
#pragma unroll
        for (int m4 = 0; m4 < 8; ++m4) {
            const float4 vr = *(const float4*)&rr[m4 * 4];
            const float4 vi = *(const float4*)&ri[m4 * 4];
            acc = fmaf(vr.x, wr[m4 * 4],     fmaf(vi.x, wi[m4 * 4],     acc));
            acc = fmaf(vr.y, wr[m4 * 4 + 1], fmaf(vi.y, wi[m4 * 4 + 1], acc));
            acc = fmaf(vr.z, wr[m4 * 4 + 2], fmaf(vi.z, wi[m4 * 4 + 2], acc));
            acc = fmaf(vr.w, wr[m4 * 4 + 3], fmaf(vi.w, wi[m4 * 4 + 3], acc));
        }
        sl[o * 132 + p] = acc * (1.0f / 65536.0f);
    }
    __syncthreads();

    // phase 2: mixer + gelu + skip + gelu
    float sp[64];
#pragma unroll
    for (int c = 0; c < 64; ++c) sp[c] = sl[c * 132 + p];
    float y[32];
#pragma unroll
    for (int oj = 0; oj < 32; ++oj) {
        const int o = half * 32 + oj;
        float a = mb[o];
        const float* mwp = &mw[o * 64];
#pragma unroll
        for (int c = 0; c < 64; ++c) a = fmaf(mwp[c], sp[c], a);
        y[oj] = gelu_f(a);
    }
    float xv[64];
#pragma unroll
    for (int c = 0; c < 64; ++c) xv[c] = xl[c * 132 + p];
#pragma unroll
    for (int oj = 0; oj < 32; ++oj) {
        const int o = half * 32 + oj;
        float a = y[oj] + scb[o];
        const float* scp = &scw[o * 64];
#pragma unroll
        for (int c = 0; c < 64; ++c) a = fmaf(scp[c], xv[c], a);
        out[((size_t)(b * 64 + o) * 256 + h) * 256 + w0 + p] = gelu_f(a);
    }
}

extern "C" void kernel_launch(void* const* d_in, const int* in_sizes, int n_in,
                              void* d_out, int out_size, void* d_ws, size_t ws_size,
                              hipStream_t stream) {
    const float* x    = (const float*)d_in[0];
    const float* wW0  = (const float*)d_in[1];
    const float* wb0  = (const float*)d_in[2];
    const float* wW1  = (const float*)d_in[3];
    const float* wb1  = (const float*)d_in[4];
    const float* wW2  = (const float*)d_in[5];
    const float* wb2  = (const float*)d_in[6];
    const float* hW0  = (const float*)d_in[7];
    const float* hb0  = (const float*)d_in[8];
    const float* hW1  = (const float*)d_in[9];
    const float* hb1  = (const float*)d_in[10];
    const float* hW2  = (const float*)d_in[11];
    const float* hb2  = (const float*)d_in[12];
    const float* Wf_re = (const float*)d_in[13];
    const float* Wf_im = (const float*)d_in[14];
    const float* mw   = (const float*)d_in[15];
    const float* mbv  = (const float*)d_in[16];
    const float* scw  = (const float*)d_in[17];
    const float* scb  = (const float*)d_in[18];

    float* ws = (float*)d_ws;
    float* wb_re   = ws;
    float* wb_im   = wb_re + 8388608;
    float* tfw_re  = wb_im + 8388608;
    float* tfw_im  = tfw_re + 2097152;
    float* tfwT    = tfw_im + 2097152;
    float* hb_re   = tfwT + 2097152;
    float* hb_im   = hb_re + 1048576;
    float* tfhw_re = hb_im + 1048576;
    float* tfhw_im = tfhw_re + 262144;
    float* proc_re = tfhw_im + 262144;
    float* proc_im = proc_re + 262144;
    float* rec_re  = proc_im + 262144;
    float* rec_im  = rec_re + 2097152;

    k_wb_mlp<<<4096, 256, 0, stream>>>(x, wW0, wb0, wW1, wb1, wW2, wb2, wb_re, wb_im);
    k_tfw<<<1024, 256, 0, stream>>>(x, wb_re, wb_im, tfw_re, tfw_im, tfwT);
    k_hb_mlp<<<512, 256, 0, stream>>>(tfwT, hW0, hb0, hW1, hb1, hW2, hb2, hb_re, hb_im);
    k_tfhw<<<256, 256, 0, stream>>>(tfw_re, tfw_im, hb_re, hb_im, tfhw_re, tfhw_im);
    k_proc<<<256, 256, 0, stream>>>(tfhw_re, tfhw_im, Wf_re, Wf_im, proc_re, proc_im);
    k_rec<<<512, 256, 0, stream>>>(proc_re, proc_im, hb_re, hb_im, rec_re, rec_im);
    k_final2<<<1024 * 2, 256, 0, stream>>>(x, wb_re, wb_im, rec_re, rec_im, mw, mbv, scw, scb,
                                           (float*)d_out);
}